// Round 1
// baseline (1195.285 us; speedup 1.0000x reference)
//
#include <hip/hip_runtime.h>
#include <hip/hip_bf16.h>

typedef _Float16 f16;
typedef _Float16 half8 __attribute__((ext_vector_type(8)));
typedef _Float16 half4v __attribute__((ext_vector_type(4)));
typedef float f32x4 __attribute__((ext_vector_type(4)));

#define B_ 4
#define S_ 3072
#define D_ 768
#define E_ 2000
#define NEG_INF -1.0e6f

// ---------------------------------------------------------------------------
// h [B,S,D] f32  ->  ht [B,D,S] f16   (LDS-tiled transpose, 64x64)
// ---------------------------------------------------------------------------
__global__ __launch_bounds__(256) void k_transpose(const float* __restrict__ h,
                                                   f16* __restrict__ ht) {
  __shared__ f16 tile[64][65];
  int b = blockIdx.z, s0 = blockIdx.x * 64, d0 = blockIdx.y * 64;
  int t = threadIdx.x, tx = t & 63, ty = t >> 6;
  const float* src = h + ((size_t)b * S_ + s0) * D_ + d0;
#pragma unroll
  for (int i = 0; i < 16; ++i) {
    int sl = i * 4 + ty;
    tile[sl][tx] = (f16)src[(size_t)sl * D_ + tx];
  }
  __syncthreads();
  f16* dst = ht + ((size_t)b * D_ + d0) * S_ + s0;
#pragma unroll
  for (int i = 0; i < 16; ++i) {
    int dl = i * 4 + ty;
    dst[(size_t)dl * S_ + tx] = tile[tx][dl];
  }
}

// ---------------------------------------------------------------------------
// z = tanh(h @ W^T + bias) -> zb f16 [B*S, D]
// 64x64 tile, 4 waves (2x2), MFMA 16x16x32 f16, K staged 32 at a time.
// ---------------------------------------------------------------------------
__global__ __launch_bounds__(256) void k_zgemm(const float* __restrict__ h,
                                               const float* __restrict__ W,
                                               const float* __restrict__ bias,
                                               f16* __restrict__ zb) {
  __shared__ f16 As[64][40];  // pad 40 elems (80B, 16B-aligned, banks spread)
  __shared__ f16 Bs[64][40];
  int i0 = blockIdx.x * 64, j0 = blockIdx.y * 64;
  int t = threadIdx.x, w = t >> 6, lane = t & 63, g = lane >> 4, li = lane & 15;
  int wi = w >> 1, wj = w & 1;

  f32x4 acc[2][2];
#pragma unroll
  for (int a = 0; a < 2; ++a)
#pragma unroll
    for (int b2 = 0; b2 < 2; ++b2) acc[a][b2] = (f32x4){0.f, 0.f, 0.f, 0.f};

  int srow = t >> 2, scol = (t & 3) * 8;
  const float* pA = h + (size_t)(i0 + srow) * D_ + scol;
  const float* pB = W + (size_t)(j0 + srow) * D_ + scol;

  for (int kc = 0; kc < D_; kc += 32) {
    float4 a0 = *(const float4*)(pA + kc);
    float4 a1 = *(const float4*)(pA + kc + 4);
    float4 b0 = *(const float4*)(pB + kc);
    float4 b1 = *(const float4*)(pB + kc + 4);
    half8 av = {(f16)a0.x, (f16)a0.y, (f16)a0.z, (f16)a0.w,
                (f16)a1.x, (f16)a1.y, (f16)a1.z, (f16)a1.w};
    half8 bv = {(f16)b0.x, (f16)b0.y, (f16)b0.z, (f16)b0.w,
                (f16)b1.x, (f16)b1.y, (f16)b1.z, (f16)b1.w};
    *(half8*)&As[srow][scol] = av;
    *(half8*)&Bs[srow][scol] = bv;
    __syncthreads();
#pragma unroll
    for (int it = 0; it < 2; ++it) {
      half8 af = *(const half8*)&As[wi * 32 + it * 16 + li][g * 8];
#pragma unroll
      for (int jt = 0; jt < 2; ++jt) {
        half8 bf = *(const half8*)&Bs[wj * 32 + jt * 16 + li][g * 8];
        acc[it][jt] =
            __builtin_amdgcn_mfma_f32_16x16x32_f16(af, bf, acc[it][jt], 0, 0, 0);
      }
    }
    __syncthreads();
  }
  // epilogue: bias + tanh + f16 store.  C layout: col=lane&15, row=g*4+r
#pragma unroll
  for (int it = 0; it < 2; ++it) {
#pragma unroll
    for (int jt = 0; jt < 2; ++jt) {
      int jj = j0 + wj * 32 + jt * 16 + li;
      float bsv = bias[jj];
#pragma unroll
      for (int r = 0; r < 4; ++r) {
        int ii = i0 + wi * 32 + it * 16 + g * 4 + r;
        float v = acc[it][jt][r] + bsv;
        zb[(size_t)ii * D_ + jj] = (f16)tanhf(v);
      }
    }
  }
}

// ---------------------------------------------------------------------------
// Fused flash attention + head max-pool.
// Block: 512 thr (8 waves), 64 queries (= 16 labels), loop S in 32-key tiles.
// QK^T: waves = (qt in 0..3, kh in 0..1) k-split; Q frags resident in regs.
// C[s,q] layout: a = K rows (LDS), b = Q rows (regs).
// PV: waves = (qw in 0..1, dh in 0..3); a = P rows (LDS), b = V rows from
// global ht (pre-transposed).  Head max-pool free in-register (r = head).
// ---------------------------------------------------------------------------
__global__ __launch_bounds__(512, 2) void k_attn(const float* __restrict__ lf,
                                                 const f16* __restrict__ zb,
                                                 const f16* __restrict__ ht,
                                                 const int* __restrict__ amask,
                                                 float* __restrict__ out_m) {
  __shared__ f16 Ks[32][776];     // K tile (also Q staging buffer) 49664 B
  __shared__ float Csum[32][68];  // k-split partial exchange        8704 B
  __shared__ f16 Pt[64][40];      // P tile (q-major)                5120 B
  __shared__ float Mrow[64];
  __shared__ float Lrow[64];
  __shared__ float Fac[64];
  __shared__ int Msk[32];

  int b = blockIdx.y;
  int q0 = blockIdx.x * 64;
  int t = threadIdx.x, w = t >> 6, lane = t & 63, g = lane >> 4, li = lane & 15;
  int qt = w & 3, kh = w >> 2;  // QK roles
  int qw = w & 1, dh = w >> 1;  // PV roles

  // ---- load Q fragments into registers (two 32-row halves staged via Ks)
  half8 qf[12];
  int qrow_l = (qt & 1) * 16 + li;
  int khalf = qt >> 1;
  for (int half = 0; half < 2; ++half) {
    for (int idx = t; idx < 32 * 192; idx += 512) {
      int row = idx / 192, c4 = idx - row * 192;
      float4 v = *(const float4*)(lf + (size_t)(q0 + half * 32 + row) * D_ + c4 * 4);
      half4v hv = {(f16)v.x, (f16)v.y, (f16)v.z, (f16)v.w};
      *(half4v*)&Ks[row][c4 * 4] = hv;
    }
    __syncthreads();
    if (khalf == half) {
#pragma unroll
      for (int f = 0; f < 12; ++f)
        qf[f] = *(const half8*)&Ks[qrow_l][kh * 384 + f * 32 + g * 8];
    }
    __syncthreads();
  }

  if (t < 64) {
    Mrow[t] = -3.0e38f;
    Lrow[t] = 0.0f;
  }

  f32x4 acc[2][12];
#pragma unroll
  for (int a = 0; a < 2; ++a)
#pragma unroll
    for (int d = 0; d < 12; ++d) acc[a][d] = (f32x4){0.f, 0.f, 0.f, 0.f};

  const f16* vbase = ht + ((size_t)b * D_ + dh * 192 + li) * S_ + g * 8;

  for (int s0 = 0; s0 < S_; s0 += 32) {
    // ---- stage K tile (zb rows, straight f16 copy, 16B chunks) ----
    for (int idx = t; idx < 32 * 96; idx += 512) {
      int row = idx / 96, c8 = idx - row * 96;
      *(uint4*)&Ks[row][c8 * 8] =
          *(const uint4*)(zb + (size_t)(b * S_ + s0 + row) * D_ + c8 * 8);
    }
    if (t < 32) Msk[t] = amask[b * S_ + s0 + t];
    __syncthreads();  // b1

    // ---- QK^T partials: each wave 32s x 16q over its 384-k half ----
    f32x4 c0 = {0.f, 0.f, 0.f, 0.f}, c1 = {0.f, 0.f, 0.f, 0.f};
#pragma unroll
    for (int ks = 0; ks < 12; ++ks) {
      half8 a0 = *(const half8*)&Ks[li][kh * 384 + ks * 32 + g * 8];
      half8 a1 = *(const half8*)&Ks[16 + li][kh * 384 + ks * 32 + g * 8];
      c0 = __builtin_amdgcn_mfma_f32_16x16x32_f16(a0, qf[ks], c0, 0, 0, 0);
      c1 = __builtin_amdgcn_mfma_f32_16x16x32_f16(a1, qf[ks], c1, 0, 0, 0);
    }
    __syncthreads();  // b2
    if (kh == 1) {
#pragma unroll
      for (int r = 0; r < 4; ++r) {
        Csum[g * 4 + r][qt * 16 + li] = c0[r];
        Csum[16 + g * 4 + r][qt * 16 + li] = c1[r];
      }
    }
    __syncthreads();  // b3
    if (kh == 0) {
      // full scores for (32 s) x (my 16 q); online softmax, wave-local per q
      float p[8];
      float vmax = -3.0e38f;
#pragma unroll
      for (int r = 0; r < 4; ++r) {
        float s0v = c0[r] + Csum[g * 4 + r][qt * 16 + li];
        float s1v = c1[r] + Csum[16 + g * 4 + r][qt * 16 + li];
        if (!Msk[g * 4 + r]) s0v = NEG_INF;
        if (!Msk[16 + g * 4 + r]) s1v = NEG_INF;
        p[r] = s0v;
        p[4 + r] = s1v;
        vmax = fmaxf(vmax, fmaxf(s0v, s1v));
      }
      vmax = fmaxf(vmax, __shfl_xor(vmax, 16));
      vmax = fmaxf(vmax, __shfl_xor(vmax, 32));
      int q = qt * 16 + li;
      float Mn = 0.f, fec = 0.f, Lp = 0.f;
      if (lane < 16) {
        float Mo = Mrow[q];
        Mn = fmaxf(Mo, vmax);
        fec = __expf(Mo - Mn);
        Mrow[q] = Mn;
        Fac[q] = fec;
        Lp = Lrow[q] * fec;
      }
      Mn = __shfl(Mn, li);  // broadcast this q's new max to all 4 g-groups
      float ts = 0.f;
#pragma unroll
      for (int r = 0; r < 8; ++r) {
        p[r] = __expf(p[r] - Mn);
        ts += p[r];
      }
      ts += __shfl_xor(ts, 16);
      ts += __shfl_xor(ts, 32);
      if (lane < 16) Lrow[q] = Lp + ts;
      half4v p0v = {(f16)p[0], (f16)p[1], (f16)p[2], (f16)p[3]};
      half4v p1v = {(f16)p[4], (f16)p[5], (f16)p[6], (f16)p[7]};
      *(half4v*)&Pt[q][g * 4] = p0v;
      *(half4v*)&Pt[q][16 + g * 4] = p1v;
    }
    __syncthreads();  // b4

    // ---- O rescale by exp(Mold - Mnew) ----
    float fr_[2][4];
#pragma unroll
    for (int qfr = 0; qfr < 2; ++qfr)
#pragma unroll
      for (int r = 0; r < 4; ++r)
        fr_[qfr][r] = Fac[qw * 32 + qfr * 16 + g * 4 + r];
#pragma unroll
    for (int qfr = 0; qfr < 2; ++qfr)
#pragma unroll
      for (int dt = 0; dt < 12; ++dt)
#pragma unroll
        for (int r = 0; r < 4; ++r) acc[qfr][dt][r] *= fr_[qfr][r];

    // ---- PV: O[q,d] += P[q,s] * V[s,d]  (V rows read from global ht) ----
    half8 pa0 = *(const half8*)&Pt[qw * 32 + li][g * 8];
    half8 pa1 = *(const half8*)&Pt[qw * 32 + 16 + li][g * 8];
    const f16* vp = vbase + s0;
#pragma unroll
    for (int dt = 0; dt < 12; ++dt) {
      half8 vb = *(const half8*)(vp + (size_t)dt * 16 * S_);
      acc[0][dt] = __builtin_amdgcn_mfma_f32_16x16x32_f16(pa0, vb, acc[0][dt], 0, 0, 0);
      acc[1][dt] = __builtin_amdgcn_mfma_f32_16x16x32_f16(pa1, vb, acc[1][dt], 0, 0, 0);
    }
  }

  // ---- epilogue: O/l, head max-pool over r (4 heads per label), store ----
#pragma unroll
  for (int qfr = 0; qfr < 2; ++qfr) {
    float rl[4];
#pragma unroll
    for (int r = 0; r < 4; ++r)
      rl[r] = 1.0f / Lrow[qw * 32 + qfr * 16 + g * 4 + r];
    int e_loc = qw * 8 + qfr * 4 + g;
    float* od = out_m + ((size_t)b * E_ + (q0 >> 2) + e_loc) * D_ + dh * 192 + li;
#pragma unroll
    for (int dt = 0; dt < 12; ++dt) {
      float mv = acc[qfr][dt][0] * rl[0];
      mv = fmaxf(mv, acc[qfr][dt][1] * rl[1]);
      mv = fmaxf(mv, acc[qfr][dt][2] * rl[2]);
      mv = fmaxf(mv, acc[qfr][dt][3] * rl[3]);
      od[dt * 16] = mv;
    }
  }
}

// ---------------------------------------------------------------------------
// logits[b,e] = sum_d cls_w[e,d]*m[b,e,d] + cls_b[e]; one wave per (b,e)
// ---------------------------------------------------------------------------
__global__ __launch_bounds__(256) void k_logits(const float* __restrict__ cw,
                                                const float* __restrict__ cb,
                                                const float* __restrict__ m,
                                                float* __restrict__ out) {
  int t = threadIdx.x, w = t >> 6, lane = t & 63;
  int rid = blockIdx.x * 4 + w;  // 0..7999
  int b = rid / E_, e = rid - b * E_;
  const float* mr = m + (size_t)rid * D_;
  const float* cr = cw + (size_t)e * D_;
  float acc = 0.f;
#pragma unroll
  for (int i = 0; i < 12; ++i) acc += cr[i * 64 + lane] * mr[i * 64 + lane];
#pragma unroll
  for (int off = 32; off >= 1; off >>= 1) acc += __shfl_xor(acc, off);
  if (lane == 0) out[rid] = acc + cb[e];
}

// ---------------------------------------------------------------------------
extern "C" void kernel_launch(void* const* d_in, const int* in_sizes, int n_in,
                              void* d_out, int out_size, void* d_ws, size_t ws_size,
                              hipStream_t stream) {
  const float* h = (const float*)d_in[0];
  const int* amask = (const int*)d_in[1];
  const float* lf = (const float*)d_in[2];
  const float* Ww = (const float*)d_in[3];
  const float* Wb = (const float*)d_in[4];
  const float* cw = (const float*)d_in[5];
  const float* cb = (const float*)d_in[6];
  float* out = (float*)d_out;

  f16* zb = (f16*)d_ws;                              // 12288*768*2 = 18874368 B
  f16* ht = (f16*)((char*)d_ws + 18874368);          // 4*768*3072*2 = 18874368 B

  k_transpose<<<dim3(48, 12, 4), 256, 0, stream>>>(h, ht);
  k_zgemm<<<dim3(192, 12), 256, 0, stream>>>(h, Ww, Wb, zb);
  k_attn<<<dim3(125, 4), 512, 0, stream>>>(lf, zb, ht, amask, out + 8000);
  k_logits<<<2000, 256, 0, stream>>>(cw, cb, out + 8000, out);
}